// Round 3
// baseline (1520.387 us; speedup 1.0000x reference)
//
#include <hip/hip_runtime.h>
#include <hip/hip_bf16.h>
#include <math.h>

// BiasFilter: x[32768,1024] -> h=gelu(LN(x@W1^T+b1)) -> g=gelu(h@W2^T+b2)
// -> scores=sigmoid(g@W3^T+b3) -> masked sequential quaternion rotation of x.
// Round 1 source, resubmitted (rounds 1-2 hit GPUAcquisitionTimeout — never ran):
// fp32 vector GEMMs (precision-critical mask decisions), 4 kernels.

#define M_TOK (8 * 4096)   // 32768 tokens
#define E_DIM 1024
#define H_DIM 512
#define NBIAS 10

__device__ __forceinline__ float gelu_erf(float t) {
    return 0.5f * t * (1.0f + erff(t * 0.70710678118654752440f));
}

// ---------------- Tiled fp32 GEMM: C[M,N] = act(A[M,K] @ B[N,K]^T + bias[N])
// BM=BN=128, BK=16, 256 threads, 8x8 micro-tile per thread.
template <int ACT>
__global__ __launch_bounds__(256) void gemm_btk(
    const float* __restrict__ A, const float* __restrict__ B,
    const float* __restrict__ bias, float* __restrict__ C,
    int M, int N, int K) {
    constexpr int BM = 128, BN = 128, BK = 16;
    __shared__ float As[BK][BM];
    __shared__ float Bs[BK][BN];

    const int tid = threadIdx.x;
    const int bm = blockIdx.y * BM;
    const int bn = blockIdx.x * BN;
    const int tx = tid & 15;        // 0..15 -> col group
    const int ty = tid >> 4;        // 0..15 -> row group

    // global staging indices: 4 lanes per row => 64B full cacheline per row
    const int lr = tid >> 2;        // 0..63
    const int lc = (tid & 3) << 2;  // 0,4,8,12

    const float* Ap0 = A + (size_t)(bm + lr) * K + lc;
    const float* Ap1 = A + (size_t)(bm + lr + 64) * K + lc;
    const float* Bp0 = B + (size_t)(bn + lr) * K + lc;
    const float* Bp1 = B + (size_t)(bn + lr + 64) * K + lc;

    float acc[8][8] = {};

    for (int k0 = 0; k0 < K; k0 += BK) {
        float4 a0 = *(const float4*)(Ap0 + k0);
        float4 a1 = *(const float4*)(Ap1 + k0);
        float4 b0 = *(const float4*)(Bp0 + k0);
        float4 b1 = *(const float4*)(Bp1 + k0);
        __syncthreads();  // previous iter's reads done before overwrite
        As[lc + 0][lr] = a0.x; As[lc + 1][lr] = a0.y;
        As[lc + 2][lr] = a0.z; As[lc + 3][lr] = a0.w;
        As[lc + 0][lr + 64] = a1.x; As[lc + 1][lr + 64] = a1.y;
        As[lc + 2][lr + 64] = a1.z; As[lc + 3][lr + 64] = a1.w;
        Bs[lc + 0][lr] = b0.x; Bs[lc + 1][lr] = b0.y;
        Bs[lc + 2][lr] = b0.z; Bs[lc + 3][lr] = b0.w;
        Bs[lc + 0][lr + 64] = b1.x; Bs[lc + 1][lr + 64] = b1.y;
        Bs[lc + 2][lr + 64] = b1.z; Bs[lc + 3][lr + 64] = b1.w;
        __syncthreads();
#pragma unroll
        for (int kk = 0; kk < BK; ++kk) {
            float ar[8], br[8];
            *(float4*)(ar + 0) = *(const float4*)&As[kk][ty * 8 + 0];
            *(float4*)(ar + 4) = *(const float4*)&As[kk][ty * 8 + 4];
            *(float4*)(br + 0) = *(const float4*)&Bs[kk][tx * 8 + 0];
            *(float4*)(br + 4) = *(const float4*)&Bs[kk][tx * 8 + 4];
#pragma unroll
            for (int i = 0; i < 8; ++i)
#pragma unroll
                for (int j = 0; j < 8; ++j)
                    acc[i][j] = fmaf(ar[i], br[j], acc[i][j]);
        }
    }

#pragma unroll
    for (int i = 0; i < 8; ++i) {
        const int row = bm + ty * 8 + i;
#pragma unroll
        for (int j = 0; j < 8; j += 4) {
            const int col = bn + tx * 8 + j;
            float4 v;
            v.x = acc[i][j + 0] + bias[col + 0];
            v.y = acc[i][j + 1] + bias[col + 1];
            v.z = acc[i][j + 2] + bias[col + 2];
            v.w = acc[i][j + 3] + bias[col + 3];
            if (ACT == 1) {
                v.x = gelu_erf(v.x); v.y = gelu_erf(v.y);
                v.z = gelu_erf(v.z); v.w = gelu_erf(v.w);
            }
            *(float4*)(C + (size_t)row * N + col) = v;
        }
    }
}

// ---------------- LayerNorm (two-pass var, numpy parity) + exact GELU, in place.
// One block of 256 threads per row of 1024 floats.
__global__ __launch_bounds__(256) void ln_gelu_kernel(
    float* __restrict__ h, const float* __restrict__ gamma,
    const float* __restrict__ beta) {
    __shared__ float sbuf[8];
    const int tid = threadIdx.x;
    float4* p = (float4*)(h + (size_t)blockIdx.x * E_DIM);
    float4 v = p[tid];

    float s = v.x + v.y + v.z + v.w;
#pragma unroll
    for (int off = 1; off < 64; off <<= 1) s += __shfl_xor(s, off);
    if ((tid & 63) == 0) sbuf[tid >> 6] = s;
    __syncthreads();
    const float mean = (sbuf[0] + sbuf[1] + sbuf[2] + sbuf[3]) * (1.0f / E_DIM);

    const float dx = v.x - mean, dy = v.y - mean, dz = v.z - mean, dw = v.w - mean;
    float s2 = dx * dx + dy * dy + dz * dz + dw * dw;
#pragma unroll
    for (int off = 1; off < 64; off <<= 1) s2 += __shfl_xor(s2, off);
    if ((tid & 63) == 0) sbuf[4 + (tid >> 6)] = s2;
    __syncthreads();
    const float var = (sbuf[4] + sbuf[5] + sbuf[6] + sbuf[7]) * (1.0f / E_DIM);
    const float rstd = 1.0f / sqrtf(var + 1e-5f);

    const float4 gm = ((const float4*)gamma)[tid];
    const float4 bt = ((const float4*)beta)[tid];
    float4 o;
    o.x = gelu_erf(dx * rstd * gm.x + bt.x);
    o.y = gelu_erf(dy * rstd * gm.y + bt.y);
    o.z = gelu_erf(dz * rstd * gm.z + bt.z);
    o.w = gelu_erf(dw * rstd * gm.w + bt.w);
    p[tid] = o;
}

// ---------------- Scores + quaternion composition + rotation.
// One wave (64 lanes) per token; 4 tokens per 256-thread block.
__global__ __launch_bounds__(256) void score_rotate_kernel(
    const float* __restrict__ g,      // [M, 512] post-GELU
    const float* __restrict__ W3,     // [10, 512]
    const float* __restrict__ b3,     // [10]
    const float* __restrict__ quats,  // [10, 4]
    const float* __restrict__ thr_p,  // [1]
    const float* __restrict__ x,      // [M, 1024]
    float* __restrict__ out) {
    const int lane = threadIdx.x & 63;
    const int wid = threadIdx.x >> 6;
    const int token = blockIdx.x * 4 + wid;

    const float4* grow = (const float4*)(g + (size_t)token * H_DIM);
    const float4 g0 = grow[lane * 2 + 0];
    const float4 g1 = grow[lane * 2 + 1];

    float dots[NBIAS];
#pragma unroll
    for (int n = 0; n < NBIAS; ++n) {
        const float4* wr = (const float4*)(W3 + n * H_DIM);
        const float4 w0 = wr[lane * 2 + 0];
        const float4 w1 = wr[lane * 2 + 1];
        float d = g0.x * w0.x + g0.y * w0.y + g0.z * w0.z + g0.w * w0.w;
        d += g1.x * w1.x + g1.y * w1.y + g1.z * w1.z + g1.w * w1.w;
        dots[n] = d;
    }
#pragma unroll
    for (int off = 1; off < 64; off <<= 1)
#pragma unroll
        for (int n = 0; n < NBIAS; ++n) dots[n] += __shfl_xor(dots[n], off);

    const float thr = thr_p[0];
    // compose q_eff = q_last_selected * ... * q_first_selected (left-accumulate)
    float qw = 1.0f, qx = 0.0f, qy = 0.0f, qz = 0.0f;
#pragma unroll
    for (int n = 0; n < NBIAS; ++n) {
        const float z = dots[n] + b3[n];
        const float s = 1.0f / (1.0f + expf(-z));
        if (s > thr) {
            const float w1 = quats[n * 4 + 0], x1 = quats[n * 4 + 1];
            const float y1 = quats[n * 4 + 2], z1 = quats[n * 4 + 3];
            const float nw = w1 * qw - x1 * qx - y1 * qy - z1 * qz;
            const float nx = w1 * qx + x1 * qw + y1 * qz - z1 * qy;
            const float ny = w1 * qy - x1 * qz + y1 * qw + z1 * qx;
            const float nz = w1 * qz + x1 * qy - y1 * qx + z1 * qw;
            qw = nw; qx = nx; qy = ny; qz = nz;
        }
    }

    const float4* xr = (const float4*)(x + (size_t)token * E_DIM);
    float4* orow = (float4*)(out + (size_t)token * E_DIM);
#pragma unroll
    for (int j = 0; j < 4; ++j) {
        const float4 p = xr[lane * 4 + j];
        float4 r;
        r.x = qw * p.x - qx * p.y - qy * p.z - qz * p.w;
        r.y = qw * p.y + qx * p.x + qy * p.w - qz * p.z;
        r.z = qw * p.z - qx * p.w + qy * p.x + qz * p.y;
        r.w = qw * p.w + qx * p.z - qy * p.y + qz * p.x;
        orow[lane * 4 + j] = r;
    }
}

extern "C" void kernel_launch(void* const* d_in, const int* in_sizes, int n_in,
                              void* d_out, int out_size, void* d_ws, size_t ws_size,
                              hipStream_t stream) {
    const float* x     = (const float*)d_in[0];
    const float* W1    = (const float*)d_in[1];
    const float* b1    = (const float*)d_in[2];
    const float* ln_g  = (const float*)d_in[3];
    const float* ln_b  = (const float*)d_in[4];
    const float* W2    = (const float*)d_in[5];
    const float* b2    = (const float*)d_in[6];
    const float* W3    = (const float*)d_in[7];
    const float* b3    = (const float*)d_in[8];
    const float* quats = (const float*)d_in[9];
    const float* thr   = (const float*)d_in[10];
    float* out = (float*)d_out;

    // workspace layout: h [M,1024] f32 (128 MB) | g [M,512] f32 (64 MB)
    float* h = (float*)d_ws;
    float* g = h + (size_t)M_TOK * E_DIM;

    dim3 blk(256);
    // K1: h = x @ W1^T + b1
    gemm_btk<0><<<dim3(E_DIM / 128, M_TOK / 128), blk, 0, stream>>>(
        x, W1, b1, h, M_TOK, E_DIM, E_DIM);
    // K2: h = gelu(LN(h)) in place
    ln_gelu_kernel<<<dim3(M_TOK), blk, 0, stream>>>(h, ln_g, ln_b);
    // K3: g = gelu(h @ W2^T + b2)
    gemm_btk<1><<<dim3(H_DIM / 128, M_TOK / 128), blk, 0, stream>>>(
        h, W2, b2, g, M_TOK, H_DIM, E_DIM);
    // K4: scores -> mask -> quaternion compose -> rotate x
    score_rotate_kernel<<<dim3(M_TOK / 4), blk, 0, stream>>>(
        g, W3, b3, quats, thr, x, out);
}

// Round 6
// 745.009 us; speedup vs baseline: 2.0408x; 2.0408x over previous
//
#include <hip/hip_runtime.h>
#include <hip/hip_bf16.h>
#include <math.h>

// BiasFilter round 4 source (3rd submit; rounds 4-5 hit GPUAcquisitionTimeout):
// bf16 hi/lo split MFMA GEMMs (3-product, fp32-accurate), m97-style 128x128 tile,
// global_load_lds staging. Runtime M-chunking to fit ws.

#define M_TOK (8 * 4096)   // 32768 tokens
#define E_DIM 1024
#define H_DIM 512
#define NBIAS 10

typedef unsigned short ushort_t;
typedef unsigned int u32;
typedef __attribute__((ext_vector_type(8))) short bf16x8;
typedef __attribute__((ext_vector_type(4))) float f32x4;

__device__ __forceinline__ float gelu_erf(float t) {
    return 0.5f * t * (1.0f + erff(t * 0.70710678118654752440f));
}
__device__ __forceinline__ float bf2f(ushort_t h) {
    return __uint_as_float((u32)h << 16);
}
__device__ __forceinline__ ushort_t f2bf(float f) {   // RNE
    u32 u = __float_as_uint(f);
    u32 r = 0x7fffu + ((u >> 16) & 1u);
    return (ushort_t)((u + r) >> 16);
}

// ---------------- split conversion: src f32 -> hi/lo bf16 (RNE; lo exact residual)
__global__ __launch_bounds__(256) void conv_split_kernel(
    const float* __restrict__ src, ushort_t* __restrict__ hi,
    ushort_t* __restrict__ lo, int n4) {
    for (int i = blockIdx.x * 256 + threadIdx.x; i < n4; i += gridDim.x * 256) {
        float4 v = ((const float4*)src)[i];
        ushort4 h, l;
        h.x = f2bf(v.x); l.x = f2bf(v.x - bf2f(h.x));
        h.y = f2bf(v.y); l.y = f2bf(v.y - bf2f(h.y));
        h.z = f2bf(v.z); l.z = f2bf(v.z - bf2f(h.z));
        h.w = f2bf(v.w); l.w = f2bf(v.w - bf2f(h.w));
        ((ushort4*)hi)[i] = h;
        ((ushort4*)lo)[i] = l;
    }
}

// ---------------- split-bf16 MFMA GEMM: C = act(A @ B^T + bias)
// A[M,K], B[N,K] given as hi/lo bf16 pairs. BM=BN=128, BK=32, 256 thr = 4 waves,
// wave-tile 64x64 (4x4 frags of 16x16x32). acc += Ah*Bh + Ah*Bl + Al*Bh.
// SPLIT_OUT=1: write Chi/Clo bf16 (bias, no act). SPLIT_OUT=0: write Cf f32 (bias+gelu).
template <int SPLIT_OUT>
__global__ __launch_bounds__(256) void gemm_mfma_split(
    const ushort_t* __restrict__ Ahi, const ushort_t* __restrict__ Alo,
    const ushort_t* __restrict__ Bhi, const ushort_t* __restrict__ Blo,
    const float* __restrict__ bias,
    ushort_t* __restrict__ Chi, ushort_t* __restrict__ Clo,
    float* __restrict__ Cf, int N, int K) {
    __shared__ ushort_t lds[4][128 * 32];   // Ahi | Alo | Bhi | Blo tiles, row-major [128][32]

    const int tid = threadIdx.x;
    const int w = tid >> 6, lane = tid & 63;
    const int bm = blockIdx.y * 128, bn = blockIdx.x * 128;
    const int wr = w >> 1, wc = w & 1;

    // wave w stages matrix w. lane -> row (lane>>2), k-elems (lane&3)*8 within 16-row segment.
    const ushort_t* gsrc = (w == 0) ? Ahi : (w == 1) ? Alo : (w == 2) ? Bhi : Blo;
    const int grow0 = (w < 2) ? bm : bn;
    const ushort_t* gbase = gsrc + (size_t)(grow0 + (lane >> 2)) * K + (lane & 3) * 8;

    f32x4 acc[4][4] = {};

    const int arow = wr * 64 + (lane & 15);
    const int brow = wc * 64 + (lane & 15);
    const int kgrp = (lane >> 4) * 8;   // elem offset of this lane's k-group

    for (int k0 = 0; k0 < K; k0 += 32) {
        __syncthreads();   // prior ds_reads done before overwrite
#pragma unroll
        for (int s = 0; s < 8; ++s) {
            __builtin_amdgcn_global_load_lds(
                (const __attribute__((address_space(1))) u32*)(const void*)(gbase + (size_t)(s * 16) * K + k0),
                (__attribute__((address_space(3))) u32*)(void*)(&lds[w][s * 16 * 32]),
                16, 0, 0);
        }
        __syncthreads();   // compiler drains vmcnt(0) before barrier -> tile visible

        bf16x8 a[2][4], b[2][4];
#pragma unroll
        for (int m = 0; m < 4; ++m) {
            a[0][m] = *(const bf16x8*)&lds[0][(arow + m * 16) * 32 + kgrp];
            a[1][m] = *(const bf16x8*)&lds[1][(arow + m * 16) * 32 + kgrp];
        }
#pragma unroll
        for (int n = 0; n < 4; ++n) {
            b[0][n] = *(const bf16x8*)&lds[2][(brow + n * 16) * 32 + kgrp];
            b[1][n] = *(const bf16x8*)&lds[3][(brow + n * 16) * 32 + kgrp];
        }
#pragma unroll
        for (int m = 0; m < 4; ++m)
#pragma unroll
            for (int n = 0; n < 4; ++n) {
                acc[m][n] = __builtin_amdgcn_mfma_f32_16x16x32_bf16(a[0][m], b[0][n], acc[m][n], 0, 0, 0);
                acc[m][n] = __builtin_amdgcn_mfma_f32_16x16x32_bf16(a[0][m], b[1][n], acc[m][n], 0, 0, 0);
                acc[m][n] = __builtin_amdgcn_mfma_f32_16x16x32_bf16(a[1][m], b[0][n], acc[m][n], 0, 0, 0);
            }
    }

    // epilogue: C/D layout col=lane&15, row=(lane>>4)*4+reg  [m89/m91-verified]
    const int crow0 = bm + wr * 64 + (lane >> 4) * 4;
    const int ccol0 = bn + wc * 64;
    const int csub = lane & 15;
#pragma unroll
    for (int m = 0; m < 4; ++m)
#pragma unroll
        for (int n = 0; n < 4; ++n) {
            const int col = ccol0 + n * 16 + csub;
            const float bv = bias[col];
#pragma unroll
            for (int r = 0; r < 4; ++r) {
                const size_t idx = (size_t)(crow0 + m * 16 + r) * N + col;
                const float v = acc[m][n][r] + bv;
                if (SPLIT_OUT) {
                    const ushort_t h = f2bf(v);
                    Chi[idx] = h;
                    Clo[idx] = f2bf(v - bf2f(h));
                } else {
                    Cf[idx] = gelu_erf(v);
                }
            }
        }
}

// ---------------- LayerNorm (two-pass var) + exact GELU on hi/lo bf16 rows, in place.
__global__ __launch_bounds__(256) void ln_gelu_split_kernel(
    ushort_t* __restrict__ hhi, ushort_t* __restrict__ hlo,
    const float* __restrict__ gamma, const float* __restrict__ beta) {
    __shared__ float sbuf[8];
    const int tid = threadIdx.x;
    const size_t base = (size_t)blockIdx.x * E_DIM + tid * 4;
    const ushort4 vh = *(const ushort4*)(hhi + base);
    const ushort4 vl = *(const ushort4*)(hlo + base);
    float f0 = bf2f(vh.x) + bf2f(vl.x);
    float f1 = bf2f(vh.y) + bf2f(vl.y);
    float f2 = bf2f(vh.z) + bf2f(vl.z);
    float f3 = bf2f(vh.w) + bf2f(vl.w);

    float s = f0 + f1 + f2 + f3;
#pragma unroll
    for (int off = 1; off < 64; off <<= 1) s += __shfl_xor(s, off);
    if ((tid & 63) == 0) sbuf[tid >> 6] = s;
    __syncthreads();
    const float mean = (sbuf[0] + sbuf[1] + sbuf[2] + sbuf[3]) * (1.0f / E_DIM);

    const float d0 = f0 - mean, d1 = f1 - mean, d2 = f2 - mean, d3 = f3 - mean;
    float s2 = d0 * d0 + d1 * d1 + d2 * d2 + d3 * d3;
#pragma unroll
    for (int off = 1; off < 64; off <<= 1) s2 += __shfl_xor(s2, off);
    if ((tid & 63) == 0) sbuf[4 + (tid >> 6)] = s2;
    __syncthreads();
    const float var = (sbuf[4] + sbuf[5] + sbuf[6] + sbuf[7]) * (1.0f / E_DIM);
    const float rstd = 1.0f / sqrtf(var + 1e-5f);

    const float4 gm = ((const float4*)gamma)[tid];
    const float4 bt = ((const float4*)beta)[tid];
    float o0 = gelu_erf(d0 * rstd * gm.x + bt.x);
    float o1 = gelu_erf(d1 * rstd * gm.y + bt.y);
    float o2 = gelu_erf(d2 * rstd * gm.z + bt.z);
    float o3 = gelu_erf(d3 * rstd * gm.w + bt.w);

    ushort4 oh, ol;
    oh.x = f2bf(o0); ol.x = f2bf(o0 - bf2f(oh.x));
    oh.y = f2bf(o1); ol.y = f2bf(o1 - bf2f(oh.y));
    oh.z = f2bf(o2); ol.z = f2bf(o2 - bf2f(oh.z));
    oh.w = f2bf(o3); ol.w = f2bf(o3 - bf2f(oh.w));
    *(ushort4*)(hhi + base) = oh;
    *(ushort4*)(hlo + base) = ol;
}

// ---------------- Scores + quaternion composition + rotation (fp32, unchanged).
__global__ __launch_bounds__(256) void score_rotate_kernel(
    const float* __restrict__ g, const float* __restrict__ W3,
    const float* __restrict__ b3, const float* __restrict__ quats,
    const float* __restrict__ thr_p, const float* __restrict__ x,
    float* __restrict__ out) {
    const int lane = threadIdx.x & 63;
    const int wid = threadIdx.x >> 6;
    const int token = blockIdx.x * 4 + wid;

    const float4* grow = (const float4*)(g + (size_t)token * H_DIM);
    const float4 g0 = grow[lane * 2 + 0];
    const float4 g1 = grow[lane * 2 + 1];

    float dots[NBIAS];
#pragma unroll
    for (int n = 0; n < NBIAS; ++n) {
        const float4* wr = (const float4*)(W3 + n * H_DIM);
        const float4 w0 = wr[lane * 2 + 0];
        const float4 w1 = wr[lane * 2 + 1];
        float d = g0.x * w0.x + g0.y * w0.y + g0.z * w0.z + g0.w * w0.w;
        d += g1.x * w1.x + g1.y * w1.y + g1.z * w1.z + g1.w * w1.w;
        dots[n] = d;
    }
#pragma unroll
    for (int off = 1; off < 64; off <<= 1)
#pragma unroll
        for (int n = 0; n < NBIAS; ++n) dots[n] += __shfl_xor(dots[n], off);

    const float thr = thr_p[0];
    float qw = 1.0f, qx = 0.0f, qy = 0.0f, qz = 0.0f;
#pragma unroll
    for (int n = 0; n < NBIAS; ++n) {
        const float z = dots[n] + b3[n];
        const float s = 1.0f / (1.0f + expf(-z));
        if (s > thr) {
            const float w1 = quats[n * 4 + 0], x1 = quats[n * 4 + 1];
            const float y1 = quats[n * 4 + 2], z1 = quats[n * 4 + 3];
            const float nw = w1 * qw - x1 * qx - y1 * qy - z1 * qz;
            const float nx = w1 * qx + x1 * qw + y1 * qz - z1 * qy;
            const float ny = w1 * qy - x1 * qz + y1 * qw + z1 * qx;
            const float nz = w1 * qz + x1 * qy - y1 * qx + z1 * qw;
            qw = nw; qx = nx; qy = ny; qz = nz;
        }
    }

    const float4* xr = (const float4*)(x + (size_t)token * E_DIM);
    float4* orow = (float4*)(out + (size_t)token * E_DIM);
#pragma unroll
    for (int j = 0; j < 4; ++j) {
        const float4 p = xr[lane * 4 + j];
        float4 r;
        r.x = qw * p.x - qx * p.y - qy * p.z - qz * p.w;
        r.y = qw * p.y + qx * p.x + qy * p.w - qz * p.z;
        r.z = qw * p.z - qx * p.w + qy * p.x + qz * p.y;
        r.w = qw * p.w + qx * p.z - qy * p.y + qz * p.x;
        orow[lane * 4 + j] = r;
    }
}

extern "C" void kernel_launch(void* const* d_in, const int* in_sizes, int n_in,
                              void* d_out, int out_size, void* d_ws, size_t ws_size,
                              hipStream_t stream) {
    const float* x     = (const float*)d_in[0];
    const float* W1    = (const float*)d_in[1];
    const float* b1    = (const float*)d_in[2];
    const float* ln_g  = (const float*)d_in[3];
    const float* ln_b  = (const float*)d_in[4];
    const float* W2    = (const float*)d_in[5];
    const float* b2    = (const float*)d_in[6];
    const float* W3    = (const float*)d_in[7];
    const float* b3    = (const float*)d_in[8];
    const float* quats = (const float*)d_in[9];
    const float* thr   = (const float*)d_in[10];
    float* out = (float*)d_out;

    // ---- workspace layout: W splits (fixed 6 MB) + chunk buffers
    char* p = (char*)d_ws;
    ushort_t* W1hi = (ushort_t*)p; p += (size_t)E_DIM * E_DIM * 2;
    ushort_t* W1lo = (ushort_t*)p; p += (size_t)E_DIM * E_DIM * 2;
    ushort_t* W2hi = (ushort_t*)p; p += (size_t)H_DIM * E_DIM * 2;
    ushort_t* W2lo = (ushort_t*)p; p += (size_t)H_DIM * E_DIM * 2;
    const size_t fixed = (size_t)(p - (char*)d_ws);

    // pick largest chunk Mc (tokens) fitting ws: per-chunk = Mc*(4KB x + 4KB h + 2KB g)/token
    int Mc = M_TOK;
    while (Mc > 128) {
        const size_t need = fixed + (size_t)Mc * (E_DIM * 2 * 2 /*x*/ + E_DIM * 2 * 2 /*h*/ + H_DIM * 4 /*g*/);
        if (need <= ws_size) break;
        Mc >>= 1;
    }
    ushort_t* xhi = (ushort_t*)p; p += (size_t)Mc * E_DIM * 2;
    ushort_t* xlo = (ushort_t*)p; p += (size_t)Mc * E_DIM * 2;
    ushort_t* hhi = (ushort_t*)p; p += (size_t)Mc * E_DIM * 2;
    ushort_t* hlo = (ushort_t*)p; p += (size_t)Mc * E_DIM * 2;
    float*    gb  = (float*)p;

    dim3 blk(256);
    // weight splits (once per call)
    {
        int n4 = E_DIM * E_DIM / 4;
        conv_split_kernel<<<dim3(min(2048, (n4 + 255) / 256)), blk, 0, stream>>>(W1, W1hi, W1lo, n4);
        n4 = H_DIM * E_DIM / 4;
        conv_split_kernel<<<dim3(min(2048, (n4 + 255) / 256)), blk, 0, stream>>>(W2, W2hi, W2lo, n4);
    }

    for (int r0 = 0; r0 < M_TOK; r0 += Mc) {
        const float* xc = x + (size_t)r0 * E_DIM;
        // split x chunk
        const int n4 = Mc * E_DIM / 4;
        conv_split_kernel<<<dim3(min(2048, (n4 + 255) / 256)), blk, 0, stream>>>(xc, xhi, xlo, n4);
        // h(split) = x @ W1^T + b1
        gemm_mfma_split<1><<<dim3(E_DIM / 128, Mc / 128), blk, 0, stream>>>(
            xhi, xlo, W1hi, W1lo, b1, hhi, hlo, nullptr, E_DIM, E_DIM);
        // h = gelu(LN(h)) in place on the split pair
        ln_gelu_split_kernel<<<dim3(Mc), blk, 0, stream>>>(hhi, hlo, ln_g, ln_b);
        // g = gelu(h @ W2^T + b2), f32
        gemm_mfma_split<0><<<dim3(H_DIM / 128, Mc / 128), blk, 0, stream>>>(
            hhi, hlo, W2hi, W2lo, b2, nullptr, nullptr, gb, H_DIM, E_DIM);
        // scores -> mask -> compose -> rotate
        score_rotate_kernel<<<dim3(Mc / 4), blk, 0, stream>>>(
            gb, W3, b3, quats, thr, xc, out + (size_t)r0 * E_DIM);
    }
}